// Round 11
// baseline (261.990 us; speedup 1.0000x reference)
//
#include <hip/hip_runtime.h>
#include <hip/hip_bf16.h>
#include <math.h>

#define N_NODES 50000
#define N_EDGES 800000
#define IN_DIM 128
#define HID_DIM 256
#define OUT_DIM 64
#define NPART 196            // ceil(N_NODES/256) coarse buckets
#define CAP 8192             // static per-bucket capacity (mean 4096, sigma 64)
#define CHUNK 2048           // edges per partition block
#define NPB ((N_EDGES + CHUNK - 1) / CHUNK)   // 391 partition blocks

typedef __attribute__((ext_vector_type(8))) short bf16x8;
typedef __attribute__((ext_vector_type(4))) short short4v;
typedef __attribute__((ext_vector_type(4))) float f32x4;

__device__ inline short f2bf(float f) {   // round-to-nearest-even bf16
    unsigned u = __float_as_uint(f);
    unsigned r = (u + 0x7fffu + ((u >> 16) & 1u)) >> 16;
    return (short)r;
}
__device__ inline float bf_lo(unsigned u) { return __uint_as_float(u << 16); }
__device__ inline float bf_hi(unsigned u) { return __uint_as_float(u & 0xffff0000u); }

// ---- blocks < NPB: pass-1 LDS-staged coarse partition by dst>>8 into static slots
// ---- blocks >= NPB: pack W1/W2 into MFMA B-frag bf16 order
__global__ __launch_bounds__(256) void part1_pack_kernel(const int* __restrict__ src,
                                                         const int* __restrict__ dst,
                                                         int* __restrict__ coarseCursor,
                                                         uint2* __restrict__ sedge,
                                                         const float* __restrict__ W1,
                                                         const float* __restrict__ W2,
                                                         short* __restrict__ Bp1,
                                                         short* __restrict__ Bp2, int E) {
    __shared__ int cnt_l[NPART];
    __shared__ int pref[NPART];
    __shared__ int gbase[NPART];
    __shared__ int ws4[4];
    __shared__ uint2 stage[CHUNK];
    int tid = threadIdx.x;
    if (blockIdx.x >= NPB) {
        // ---- pack path ----
        int idx = (blockIdx.x - NPB) * 256 + tid;
        const float* W; short* Bp; int N;
        const int T1 = (IN_DIM / 32) * (HID_DIM / 16) * 64;    // 4096
        const int T2 = (HID_DIM / 32) * (OUT_DIM / 16) * 64;   // 2048
        if (idx < T1) { W = W1; Bp = Bp1; N = HID_DIM; }
        else { idx -= T1; if (idx >= T2) return; W = W2; Bp = Bp2; N = OUT_DIM; }
        int lane = idx & 63;
        int frag = idx >> 6;
        int ntiles = N >> 4;
        int nt = frag % ntiles;
        int kt = frag / ntiles;
        int col = nt * 16 + (lane & 15);
        int krow = kt * 32 + (lane >> 4) * 8;
        bf16x8 pk;
        #pragma unroll
        for (int j = 0; j < 8; j++) pk[j] = f2bf(W[(size_t)(krow + j) * N + col]);
        *((bf16x8*)(Bp + (size_t)idx * 8)) = pk;
        return;
    }
    int e0 = blockIdx.x * CHUNK;
    if (tid < NPART) cnt_l[tid] = 0;
    __syncthreads();
    int es[CHUNK / 256], ed[CHUNK / 256];
    #pragma unroll
    for (int j = 0; j < CHUNK / 256; j++) {
        int e = e0 + j * 256 + tid;
        if (e < E) {
            es[j] = src[e]; ed[j] = dst[e];
            atomicAdd(&cnt_l[ed[j] >> 8], 1);
        } else ed[j] = -1;
    }
    __syncthreads();
    int lane = tid & 63, wid = tid >> 6;
    int v = (tid < NPART) ? cnt_l[tid] : 0;
    int s = v;
    #pragma unroll
    for (int off = 1; off < 64; off <<= 1) {
        int t = __shfl_up(s, off, 64);
        if (lane >= off) s += t;
    }
    if (lane == 63) ws4[wid] = s;
    __syncthreads();
    int wp = 0;
    #pragma unroll
    for (int w = 0; w < 4; w++) wp += (w < wid) ? ws4[w] : 0;
    int excl = s - v + wp;
    if (tid < NPART) pref[tid] = excl;
    __syncthreads();
    if (tid < NPART) cnt_l[tid] = excl;   // reuse as local cursor
    __syncthreads();
    #pragma unroll
    for (int j = 0; j < CHUNK / 256; j++) {
        if (ed[j] >= 0) {
            int c = ed[j] >> 8;
            int p = atomicAdd(&cnt_l[c], 1);
            stage[p] = make_uint2((unsigned)es[j], (unsigned)ed[j]);
        }
    }
    __syncthreads();
    if (tid < NPART) {
        int cl = cnt_l[tid] - pref[tid];
        gbase[tid] = (cl > 0) ? (tid * CAP + atomicAdd(&coarseCursor[tid], cl)) : 0;
    }
    __syncthreads();
    int total = (e0 + CHUNK <= E) ? CHUNK : (E - e0);
    for (int i = tid; i < total; i += 256) {
        uint2 ev = stage[i];
        int c = (int)(ev.y >> 8);
        sedge[gbase[c] + (i - pref[c])] = ev;
    }
}

// ---- pass 2 (one block per coarse bucket): local per-node count + scan -> offs/cnt/dis,
// ---- fine scatter with LDS cursors, then prep xb rows for this block's own 256 nodes.
__global__ __launch_bounds__(256) void part2_kernel(const uint2* __restrict__ sedge,
                                                    const int* __restrict__ coarseCnt,
                                                    int* __restrict__ offs,
                                                    int* __restrict__ cntg,
                                                    float* __restrict__ dis,
                                                    int* __restrict__ ssrc,
                                                    const float* __restrict__ x,
                                                    short* __restrict__ xb, int n) {
    __shared__ int kcnt[256];
    __shared__ int ws4[4];
    __shared__ float sdis[256];
    int b = blockIdx.x, tid = threadIdx.x;
    int base = b * CAP;
    int cb = coarseCnt[b];
    kcnt[tid] = 0;
    __syncthreads();
    for (int i = tid; i < cb; i += 256) {
        uint2 ev = sedge[base + i];
        atomicAdd(&kcnt[ev.y & 255], 1);
    }
    __syncthreads();
    int v = kcnt[tid];
    int lane = tid & 63, wid = tid >> 6;
    int s = v;
    #pragma unroll
    for (int off = 1; off < 64; off <<= 1) {
        int t = __shfl_up(s, off, 64);
        if (lane >= off) s += t;
    }
    if (lane == 63) ws4[wid] = s;
    __syncthreads();
    int wp = 0;
    #pragma unroll
    for (int w = 0; w < 4; w++) wp += (w < wid) ? ws4[w] : 0;
    int excl = s - v + wp;
    int node = b * 256 + tid;
    float dn = rsqrtf((float)v + 1.0f);   // +1 self-loop
    if (node < n) {
        offs[node] = base + excl;
        cntg[node] = v;
        dis[node] = dn;
    }
    sdis[tid] = dn;
    __syncthreads();
    kcnt[tid] = base + excl;              // becomes cursor
    __syncthreads();
    for (int i = tid; i < cb; i += 256) {
        uint2 ev = sedge[base + i];
        int pos = atomicAdd(&kcnt[ev.y & 255], 1);
        ssrc[pos] = (int)ev.x;
    }
    // prep: xb[nd,:] = bf16(x[nd,:] * dis[nd]) for this block's nodes, coalesced
    int rlane = tid & 31, rgrp = tid >> 5;
    for (int rb = 0; rb < 32; rb++) {
        int row = rb * 8 + rgrp;
        int nd = b * 256 + row;
        if (nd >= n) break;
        float d2 = sdis[row];
        float4 vv = ((const float4*)(x + (size_t)nd * IN_DIM))[rlane];
        short4v o = {f2bf(vv.x * d2), f2bf(vv.y * d2), f2bf(vv.z * d2), f2bf(vv.w * d2)};
        *((short4v*)(xb + (size_t)nd * IN_DIM + rlane * 4)) = o;
    }
}

// ======= fused aggregate + 2-layer MFMA GEMM =======
// Each block owns 64 nodes (4 waves x 16). Phase 0: each wave aggregates its 16 nodes
// (wave-uniform shuffle rounds, gated FMA) into wave-private LDS rows (A-tile, stride 136
// shorts -> 2-way bank alias, free). Phase A: h1 = relu(A@W1+b1) from LDS A-frags; h1 tile
// overwrites the same LDS region (A dead; same-wave DS ops are in-order) with stride 264.
// Phase B: h2 = (h1@W2)*dis from LDS. No __syncthreads anywhere (all LDS is wave-private).
#define A_STRIDE 136   // 128 + 8 shorts: 272B row stride -> bank (4r+c)%32, 2-way = free
#define H_STRIDE 264   // 256 + 8 shorts: 528B row stride -> bank (4r+c)%32, 2-way = free
__global__ __launch_bounds__(256) void agg_gemm_kernel(const short* __restrict__ xb,
                                                       const int* __restrict__ ssrc,
                                                       const int* __restrict__ offs,
                                                       const int* __restrict__ cnt,
                                                       const float* __restrict__ dis,
                                                       const short* __restrict__ Bp1,
                                                       const short* __restrict__ Bp2,
                                                       const float* __restrict__ b1,
                                                       short* __restrict__ h2, int M) {
    __shared__ short lds[4][16 * H_STRIDE];   // 33.8 KB total
    int lane = threadIdx.x & 63;
    int w = threadIdx.x >> 6;
    int rowBase = blockIdx.x * 64 + w * 16;
    int grp = lane >> 3, l8 = lane & 7;

    // ---- phase 0: aggregate 16 nodes into LDS A-tile ----
    for (int m = 0; m < 16; m++) {
        int node = rowBase + m;                      // wave-uniform
        if (node < M) {
            int start = offs[node], c = cnt[node];
            int vidx = (lane < c) ? ssrc[start + lane] : 0;
            float acc[16] = {};
            int lim = (c < 64) ? c : 64;
            int rounds = (lim + 15) >> 4;            // wave-uniform trip count
            for (int r = 0; r < rounds; r++) {
                int j0 = r * 16 + grp;
                int j1 = j0 + 8;
                int i0 = (j0 < 63) ? j0 : 63;
                int i1 = (j1 < 63) ? j1 : 63;
                int s0 = __shfl(vidx, i0, 64);
                int s1 = __shfl(vidx, i1, 64);
                float g0 = (j0 < lim) ? 1.0f : 0.0f;
                float g1 = (j1 < lim) ? 1.0f : 0.0f;
                const uint4* r0 = (const uint4*)(xb + (size_t)s0 * IN_DIM + l8 * 16);
                const uint4* r1 = (const uint4*)(xb + (size_t)s1 * IN_DIM + l8 * 16);
                uint4 a0 = r0[0], a1 = r0[1];
                uint4 b0 = r1[0], b1v = r1[1];
                acc[0]  += g0 * bf_lo(a0.x); acc[1]  += g0 * bf_hi(a0.x);
                acc[2]  += g0 * bf_lo(a0.y); acc[3]  += g0 * bf_hi(a0.y);
                acc[4]  += g0 * bf_lo(a0.z); acc[5]  += g0 * bf_hi(a0.z);
                acc[6]  += g0 * bf_lo(a0.w); acc[7]  += g0 * bf_hi(a0.w);
                acc[8]  += g0 * bf_lo(a1.x); acc[9]  += g0 * bf_hi(a1.x);
                acc[10] += g0 * bf_lo(a1.y); acc[11] += g0 * bf_hi(a1.y);
                acc[12] += g0 * bf_lo(a1.z); acc[13] += g0 * bf_hi(a1.z);
                acc[14] += g0 * bf_lo(a1.w); acc[15] += g0 * bf_hi(a1.w);
                acc[0]  += g1 * bf_lo(b0.x); acc[1]  += g1 * bf_hi(b0.x);
                acc[2]  += g1 * bf_lo(b0.y); acc[3]  += g1 * bf_hi(b0.y);
                acc[4]  += g1 * bf_lo(b0.z); acc[5]  += g1 * bf_hi(b0.z);
                acc[6]  += g1 * bf_lo(b0.w); acc[7]  += g1 * bf_hi(b0.w);
                acc[8]  += g1 * bf_lo(b1v.x); acc[9]  += g1 * bf_hi(b1v.x);
                acc[10] += g1 * bf_lo(b1v.y); acc[11] += g1 * bf_hi(b1v.y);
                acc[12] += g1 * bf_lo(b1v.z); acc[13] += g1 * bf_hi(b1v.z);
                acc[14] += g1 * bf_lo(b1v.w); acc[15] += g1 * bf_hi(b1v.w);
            }
            // rare tail c > 64: per-lane loads, no shuffles
            for (int j = 64 + grp; j < c; j += 8) {
                int s0 = ssrc[start + j];
                const uint4* r0 = (const uint4*)(xb + (size_t)s0 * IN_DIM + l8 * 16);
                uint4 a0 = r0[0], a1 = r0[1];
                acc[0]  += bf_lo(a0.x); acc[1]  += bf_hi(a0.x);
                acc[2]  += bf_lo(a0.y); acc[3]  += bf_hi(a0.y);
                acc[4]  += bf_lo(a0.z); acc[5]  += bf_hi(a0.z);
                acc[6]  += bf_lo(a0.w); acc[7]  += bf_hi(a0.w);
                acc[8]  += bf_lo(a1.x); acc[9]  += bf_hi(a1.x);
                acc[10] += bf_lo(a1.y); acc[11] += bf_hi(a1.y);
                acc[12] += bf_lo(a1.z); acc[13] += bf_hi(a1.z);
                acc[14] += bf_lo(a1.w); acc[15] += bf_hi(a1.w);
            }
            #pragma unroll
            for (int k = 0; k < 16; k++) {
                acc[k] += __shfl_xor(acc[k], 8, 64);
                acc[k] += __shfl_xor(acc[k], 16, 64);
                acc[k] += __shfl_xor(acc[k], 32, 64);
            }
            if (grp == 0) {
                float dn = dis[node];
                const uint4* rs = (const uint4*)(xb + (size_t)node * IN_DIM + l8 * 16);
                uint4 a0 = rs[0], a1 = rs[1];
                acc[0]  += bf_lo(a0.x); acc[1]  += bf_hi(a0.x);
                acc[2]  += bf_lo(a0.y); acc[3]  += bf_hi(a0.y);
                acc[4]  += bf_lo(a0.z); acc[5]  += bf_hi(a0.z);
                acc[6]  += bf_lo(a0.w); acc[7]  += bf_hi(a0.w);
                acc[8]  += bf_lo(a1.x); acc[9]  += bf_hi(a1.x);
                acc[10] += bf_lo(a1.y); acc[11] += bf_hi(a1.y);
                acc[12] += bf_lo(a1.z); acc[13] += bf_hi(a1.z);
                acc[14] += bf_lo(a1.w); acc[15] += bf_hi(a1.w);
                bf16x8 o0, o1;
                #pragma unroll
                for (int k = 0; k < 8; k++) {
                    o0[k] = f2bf(acc[k] * dn);
                    o1[k] = f2bf(acc[k + 8] * dn);
                }
                short* d0 = &lds[w][m * A_STRIDE + l8 * 16];
                *((bf16x8*)d0) = o0;
                *((bf16x8*)(d0 + 8)) = o1;
            }
        } else if (grp == 0) {
            bf16x8 z = {};
            short* d0 = &lds[w][m * A_STRIDE + l8 * 16];
            *((bf16x8*)d0) = z;
            *((bf16x8*)(d0 + 8)) = z;
        }
    }

    // ---- phase A: h1 = relu(A @ W1 + b1), K=128, N=256; A-frags from LDS ----
    int arowL = lane & 15;
    int kseg = lane >> 4;
    int col0 = lane & 15;
    constexpr int NT1 = HID_DIM / 16;   // 16
    f32x4 acc1[NT1] = {};
    #pragma unroll
    for (int kt = 0; kt < IN_DIM / 32; kt++) {
        bf16x8 a = *((const bf16x8*)&lds[w][arowL * A_STRIDE + kt * 32 + kseg * 8]);
        #pragma unroll
        for (int nt = 0; nt < NT1; nt++) {
            bf16x8 b = *((const bf16x8*)(Bp1 + ((size_t)(kt * NT1 + nt) * 64 + lane) * 8));
            acc1[nt] = __builtin_amdgcn_mfma_f32_16x16x32_bf16(a, b, acc1[nt], 0, 0, 0);
        }
    }
    // epilogue: relu+bias, write h1 tile into the SAME LDS region (A dead, in-order DS)
    #pragma unroll
    for (int nt = 0; nt < NT1; nt++) {
        float bv = b1[nt * 16 + col0];
        #pragma unroll
        for (int i = 0; i < 4; i++) {
            float v = fmaxf(acc1[nt][i] + bv, 0.0f);
            lds[w][(kseg * 4 + i) * H_STRIDE + nt * 16 + col0] = f2bf(v);
        }
    }
    // ---- phase B: h2 = (h1 @ W2) * dis, K=256, N=64 ----
    constexpr int NT2 = OUT_DIM / 16;   // 4
    f32x4 acc2[NT2] = {};
    #pragma unroll
    for (int kt = 0; kt < HID_DIM / 32; kt++) {
        bf16x8 a = *((const bf16x8*)&lds[w][arowL * H_STRIDE + kt * 32 + kseg * 8]);
        #pragma unroll
        for (int nt = 0; nt < NT2; nt++) {
            bf16x8 b = *((const bf16x8*)(Bp2 + ((size_t)(kt * NT2 + nt) * 64 + lane) * 8));
            acc2[nt] = __builtin_amdgcn_mfma_f32_16x16x32_bf16(a, b, acc2[nt], 0, 0, 0);
        }
    }
    #pragma unroll
    for (int i = 0; i < 4; i++) {
        int r = rowBase + kseg * 4 + i;
        if (r >= M) continue;
        float sc = dis[r];
        #pragma unroll
        for (int nt = 0; nt < NT2; nt++)
            h2[(size_t)r * OUT_DIM + nt * 16 + col0] = f2bf(acc2[nt][i] * sc);
    }
}

// ------- layer-2 aggregate: wave per node, 8 groups x 8 lanes (16 B/lane/row),
// ------- wave-uniform shuffle rounds (gated FMA), + self-loop + bias + log_softmax ----
__global__ void agg2_kernel(const short* __restrict__ h2, const int* __restrict__ ssrc,
                            const int* __restrict__ offs, const int* __restrict__ cnt,
                            const float* __restrict__ dis, const float* __restrict__ b2,
                            float* __restrict__ out, int n) {
    int lane = threadIdx.x & 63;
    int node = blockIdx.x * 4 + (threadIdx.x >> 6);
    if (node >= n) return;
    int grp = lane >> 3, l8 = lane & 7;
    int start = offs[node], c = cnt[node];
    int vidx = (lane < c) ? ssrc[start + lane] : 0;
    float acc[8] = {};
    int lim = (c < 64) ? c : 64;
    int rounds = (lim + 15) >> 4;                     // wave-uniform
    for (int r = 0; r < rounds; r++) {
        int j0 = r * 16 + grp;
        int j1 = j0 + 8;
        int i0 = (j0 < 63) ? j0 : 63;
        int i1 = (j1 < 63) ? j1 : 63;
        int s0 = __shfl(vidx, i0, 64);
        int s1 = __shfl(vidx, i1, 64);
        float g0 = (j0 < lim) ? 1.0f : 0.0f;
        float g1 = (j1 < lim) ? 1.0f : 0.0f;
        uint4 p0 = *((const uint4*)(h2 + (size_t)s0 * OUT_DIM + l8 * 8));
        uint4 p1 = *((const uint4*)(h2 + (size_t)s1 * OUT_DIM + l8 * 8));
        acc[0] += g0 * bf_lo(p0.x); acc[1] += g0 * bf_hi(p0.x);
        acc[2] += g0 * bf_lo(p0.y); acc[3] += g0 * bf_hi(p0.y);
        acc[4] += g0 * bf_lo(p0.z); acc[5] += g0 * bf_hi(p0.z);
        acc[6] += g0 * bf_lo(p0.w); acc[7] += g0 * bf_hi(p0.w);
        acc[0] += g1 * bf_lo(p1.x); acc[1] += g1 * bf_hi(p1.x);
        acc[2] += g1 * bf_lo(p1.y); acc[3] += g1 * bf_hi(p1.y);
        acc[4] += g1 * bf_lo(p1.z); acc[5] += g1 * bf_hi(p1.z);
        acc[6] += g1 * bf_lo(p1.w); acc[7] += g1 * bf_hi(p1.w);
    }
    // rare tail c > 64
    for (int j = 64 + grp; j < c; j += 8) {
        int s0 = ssrc[start + j];
        uint4 p0 = *((const uint4*)(h2 + (size_t)s0 * OUT_DIM + l8 * 8));
        acc[0] += bf_lo(p0.x); acc[1] += bf_hi(p0.x); acc[2] += bf_lo(p0.y); acc[3] += bf_hi(p0.y);
        acc[4] += bf_lo(p0.z); acc[5] += bf_hi(p0.z); acc[6] += bf_lo(p0.w); acc[7] += bf_hi(p0.w);
    }
    #pragma unroll
    for (int k = 0; k < 8; k++) {
        acc[k] += __shfl_xor(acc[k], 8, 64);
        acc[k] += __shfl_xor(acc[k], 16, 64);
        acc[k] += __shfl_xor(acc[k], 32, 64);
    }
    // self-loop + dn scale + bias (cols l8*8 .. l8*8+7)
    float dn = dis[node];
    uint4 pv = *((const uint4*)(h2 + (size_t)node * OUT_DIM + l8 * 8));
    float4 bb0 = ((const float4*)b2)[l8 * 2];
    float4 bb1 = ((const float4*)b2)[l8 * 2 + 1];
    acc[0] = (acc[0] + bf_lo(pv.x)) * dn + bb0.x;
    acc[1] = (acc[1] + bf_hi(pv.x)) * dn + bb0.y;
    acc[2] = (acc[2] + bf_lo(pv.y)) * dn + bb0.z;
    acc[3] = (acc[3] + bf_hi(pv.y)) * dn + bb0.w;
    acc[4] = (acc[4] + bf_lo(pv.z)) * dn + bb1.x;
    acc[5] = (acc[5] + bf_hi(pv.z)) * dn + bb1.y;
    acc[6] = (acc[6] + bf_lo(pv.w)) * dn + bb1.z;
    acc[7] = (acc[7] + bf_hi(pv.w)) * dn + bb1.w;
    // log_softmax over 64 cols (8 l8-lanes x 8 regs)
    float m = acc[0];
    #pragma unroll
    for (int k = 1; k < 8; k++) m = fmaxf(m, acc[k]);
    #pragma unroll
    for (int off = 1; off < 8; off <<= 1) m = fmaxf(m, __shfl_xor(m, off, 64));
    float ex = 0.0f;
    #pragma unroll
    for (int k = 0; k < 8; k++) ex += expf(acc[k] - m);
    #pragma unroll
    for (int off = 1; off < 8; off <<= 1) ex += __shfl_xor(ex, off, 64);
    float ls = m + logf(ex);
    if (grp == 0) {
        float4 o0 = {acc[0] - ls, acc[1] - ls, acc[2] - ls, acc[3] - ls};
        float4 o1 = {acc[4] - ls, acc[5] - ls, acc[6] - ls, acc[7] - ls};
        ((float4*)(out + (size_t)node * OUT_DIM))[l8 * 2] = o0;
        ((float4*)(out + (size_t)node * OUT_DIM))[l8 * 2 + 1] = o1;
    }
}

extern "C" void kernel_launch(void* const* d_in, const int* in_sizes, int n_in,
                              void* d_out, int out_size, void* d_ws, size_t ws_size,
                              hipStream_t stream) {
    const float* x  = (const float*)d_in[0];
    const int*   ei = (const int*)d_in[1];
    const float* W1 = (const float*)d_in[2];
    const float* b1 = (const float*)d_in[3];
    const float* W2 = (const float*)d_in[4];
    const float* b2 = (const float*)d_in[5];
    float* out = (float*)d_out;
    char* ws = (char*)d_ws;

    const int* srcp = ei;
    const int* dstp = ei + N_EDGES;

    // workspace layout (256-aligned)
    int*   coarseCursor = (int*)(ws);              // 196 int (doubles as coarseCnt)
    int*   offs   = (int*)(ws + 4096);             // 50000 int
    int*   cntg   = (int*)(ws + 262144);           // 50000 int
    float* dis    = (float*)(ws + 524288);         // 50000 f32
    short* Bp1    = (short*)(ws + 786432);         // 64 KB
    short* Bp2    = (short*)(ws + 851968);         // 32 KB
    int*   ssrc   = (int*)(ws + 917504);           // 196*8192*4 = 6.4 MB
    uint2* sedge  = (uint2*)(ws + 7340032);        // 196*8192*8 = 12.8 MB
    short* xb     = (short*)(ws + 20185088);       // 12.8 MB
    short* h2     = (short*)(ws + 32985088);       // 6.4 MB bf16

    hipMemsetAsync(coarseCursor, 0, NPART * 4, stream);

    part1_pack_kernel<<<NPB + 24, 256, 0, stream>>>(srcp, dstp, coarseCursor, sedge,
                                                    W1, W2, Bp1, Bp2, N_EDGES);
    part2_kernel<<<NPART, 256, 0, stream>>>(sedge, coarseCursor, offs, cntg, dis, ssrc,
                                            x, xb, N_NODES);
    agg_gemm_kernel<<<(N_NODES + 63) / 64, 256, 0, stream>>>(xb, ssrc, offs, cntg, dis,
                                                             Bp1, Bp2, b1, h2, N_NODES);
    agg2_kernel<<<(N_NODES + 3) / 4, 256, 0, stream>>>(h2, ssrc, offs, cntg, dis, b2, out, N_NODES);
}

// Round 12
// 204.925 us; speedup vs baseline: 1.2785x; 1.2785x over previous
//
#include <hip/hip_runtime.h>
#include <hip/hip_bf16.h>
#include <math.h>

#define N_NODES 50000
#define N_EDGES 800000
#define IN_DIM 128
#define HID_DIM 256
#define OUT_DIM 64
#define NPART 196            // ceil(N_NODES/256) coarse buckets
#define CAP 8192             // static per-bucket capacity (mean 4096, sigma 64)
#define CHUNK 2048           // edges per partition block
#define NPB ((N_EDGES + CHUNK - 1) / CHUNK)   // 391 partition blocks

typedef __attribute__((ext_vector_type(8))) short bf16x8;
typedef __attribute__((ext_vector_type(4))) short short4v;
typedef __attribute__((ext_vector_type(4))) float f32x4;

__device__ inline short f2bf(float f) {   // round-to-nearest-even bf16
    unsigned u = __float_as_uint(f);
    unsigned r = (u + 0x7fffu + ((u >> 16) & 1u)) >> 16;
    return (short)r;
}
__device__ inline float bf_lo(unsigned u) { return __uint_as_float(u << 16); }
__device__ inline float bf_hi(unsigned u) { return __uint_as_float(u & 0xffff0000u); }

// ---- blocks < NPB: pass-1 LDS-staged coarse partition by dst>>8 into static slots
// ---- blocks >= NPB: pack W1/W2 into MFMA B-frag bf16 order
__global__ __launch_bounds__(256) void part1_pack_kernel(const int* __restrict__ src,
                                                         const int* __restrict__ dst,
                                                         int* __restrict__ coarseCursor,
                                                         uint2* __restrict__ sedge,
                                                         const float* __restrict__ W1,
                                                         const float* __restrict__ W2,
                                                         short* __restrict__ Bp1,
                                                         short* __restrict__ Bp2, int E) {
    __shared__ int cnt_l[NPART];
    __shared__ int pref[NPART];
    __shared__ int gbase[NPART];
    __shared__ int ws4[4];
    __shared__ uint2 stage[CHUNK];
    int tid = threadIdx.x;
    if (blockIdx.x >= NPB) {
        // ---- pack path ----
        int idx = (blockIdx.x - NPB) * 256 + tid;
        const float* W; short* Bp; int N;
        const int T1 = (IN_DIM / 32) * (HID_DIM / 16) * 64;    // 4096
        const int T2 = (HID_DIM / 32) * (OUT_DIM / 16) * 64;   // 2048
        if (idx < T1) { W = W1; Bp = Bp1; N = HID_DIM; }
        else { idx -= T1; if (idx >= T2) return; W = W2; Bp = Bp2; N = OUT_DIM; }
        int lane = idx & 63;
        int frag = idx >> 6;
        int ntiles = N >> 4;
        int nt = frag % ntiles;
        int kt = frag / ntiles;
        int col = nt * 16 + (lane & 15);
        int krow = kt * 32 + (lane >> 4) * 8;
        bf16x8 pk;
        #pragma unroll
        for (int j = 0; j < 8; j++) pk[j] = f2bf(W[(size_t)(krow + j) * N + col]);
        *((bf16x8*)(Bp + (size_t)idx * 8)) = pk;
        return;
    }
    int e0 = blockIdx.x * CHUNK;
    if (tid < NPART) cnt_l[tid] = 0;
    __syncthreads();
    int es[CHUNK / 256], ed[CHUNK / 256];
    #pragma unroll
    for (int j = 0; j < CHUNK / 256; j++) {
        int e = e0 + j * 256 + tid;
        if (e < E) {
            es[j] = src[e]; ed[j] = dst[e];
            atomicAdd(&cnt_l[ed[j] >> 8], 1);
        } else ed[j] = -1;
    }
    __syncthreads();
    int lane = tid & 63, wid = tid >> 6;
    int v = (tid < NPART) ? cnt_l[tid] : 0;
    int s = v;
    #pragma unroll
    for (int off = 1; off < 64; off <<= 1) {
        int t = __shfl_up(s, off, 64);
        if (lane >= off) s += t;
    }
    if (lane == 63) ws4[wid] = s;
    __syncthreads();
    int wp = 0;
    #pragma unroll
    for (int w = 0; w < 4; w++) wp += (w < wid) ? ws4[w] : 0;
    int excl = s - v + wp;
    if (tid < NPART) pref[tid] = excl;
    __syncthreads();
    if (tid < NPART) cnt_l[tid] = excl;   // reuse as local cursor
    __syncthreads();
    #pragma unroll
    for (int j = 0; j < CHUNK / 256; j++) {
        if (ed[j] >= 0) {
            int c = ed[j] >> 8;
            int p = atomicAdd(&cnt_l[c], 1);
            stage[p] = make_uint2((unsigned)es[j], (unsigned)ed[j]);
        }
    }
    __syncthreads();
    if (tid < NPART) {
        int cl = cnt_l[tid] - pref[tid];
        gbase[tid] = (cl > 0) ? (tid * CAP + atomicAdd(&coarseCursor[tid], cl)) : 0;
    }
    __syncthreads();
    int total = (e0 + CHUNK <= E) ? CHUNK : (E - e0);
    for (int i = tid; i < total; i += 256) {
        uint2 ev = stage[i];
        int c = (int)(ev.y >> 8);
        sedge[gbase[c] + (i - pref[c])] = ev;
    }
}

// ---- pass 2 (one block per coarse bucket): local per-node count + scan -> offs/cnt/dis,
// ---- fine scatter with LDS cursors, then prep xb rows for this block's own 256 nodes.
__global__ __launch_bounds__(256) void part2_kernel(const uint2* __restrict__ sedge,
                                                    const int* __restrict__ coarseCnt,
                                                    int* __restrict__ offs,
                                                    int* __restrict__ cntg,
                                                    float* __restrict__ dis,
                                                    int* __restrict__ ssrc,
                                                    const float* __restrict__ x,
                                                    short* __restrict__ xb, int n) {
    __shared__ int kcnt[256];
    __shared__ int ws4[4];
    __shared__ float sdis[256];
    int b = blockIdx.x, tid = threadIdx.x;
    int base = b * CAP;
    int cb = coarseCnt[b];
    kcnt[tid] = 0;
    __syncthreads();
    for (int i = tid; i < cb; i += 256) {
        uint2 ev = sedge[base + i];
        atomicAdd(&kcnt[ev.y & 255], 1);
    }
    __syncthreads();
    int v = kcnt[tid];
    int lane = tid & 63, wid = tid >> 6;
    int s = v;
    #pragma unroll
    for (int off = 1; off < 64; off <<= 1) {
        int t = __shfl_up(s, off, 64);
        if (lane >= off) s += t;
    }
    if (lane == 63) ws4[wid] = s;
    __syncthreads();
    int wp = 0;
    #pragma unroll
    for (int w = 0; w < 4; w++) wp += (w < wid) ? ws4[w] : 0;
    int excl = s - v + wp;
    int node = b * 256 + tid;
    float dn = rsqrtf((float)v + 1.0f);   // +1 self-loop
    if (node < n) {
        offs[node] = base + excl;
        cntg[node] = v;
        dis[node] = dn;
    }
    sdis[tid] = dn;
    __syncthreads();
    kcnt[tid] = base + excl;              // becomes cursor
    __syncthreads();
    for (int i = tid; i < cb; i += 256) {
        uint2 ev = sedge[base + i];
        int pos = atomicAdd(&kcnt[ev.y & 255], 1);
        ssrc[pos] = (int)ev.x;
    }
    // prep: xb[nd,:] = bf16(x[nd,:] * dis[nd]) for this block's nodes, coalesced
    int rlane = tid & 31, rgrp = tid >> 5;
    for (int rb = 0; rb < 32; rb++) {
        int row = rb * 8 + rgrp;
        int nd = b * 256 + row;
        if (nd >= n) break;
        float d2 = sdis[row];
        float4 vv = ((const float4*)(x + (size_t)nd * IN_DIM))[rlane];
        short4v o = {f2bf(vv.x * d2), f2bf(vv.y * d2), f2bf(vv.z * d2), f2bf(vv.w * d2)};
        *((short4v*)(xb + (size_t)nd * IN_DIM + rlane * 4)) = o;
    }
}

// ------- layer-1 aggregate: wave per node, 8 groups x 8 lanes (32 B/lane/row).
// ------- Edge indices wave-loaded once; distributed via WAVE-UNIFORM __shfl rounds
// ------- (all 64 lanes active in every shuffle; out-of-range edges gated by 0/1 FMA).
// ------- ds_bpermute is undefined for inactive source lanes -> never shuffle divergently.
__global__ void agg1_kernel(const short* __restrict__ xb, const int* __restrict__ ssrc,
                            const int* __restrict__ offs, const int* __restrict__ cnt,
                            const float* __restrict__ dis, short* __restrict__ aggx, int n) {
    int lane = threadIdx.x & 63;
    int node = blockIdx.x * 4 + (threadIdx.x >> 6);
    if (node >= n) return;
    int grp = lane >> 3, l8 = lane & 7;
    int start = offs[node], c = cnt[node];
    int vidx = (lane < c) ? ssrc[start + lane] : 0;   // all indices in one coalesced load
    float acc[16] = {};
    int lim = (c < 64) ? c : 64;
    int rounds = (lim + 15) >> 4;                     // wave-uniform trip count
    for (int r = 0; r < rounds; r++) {
        int j0 = r * 16 + grp;
        int j1 = j0 + 8;
        int i0 = (j0 < 63) ? j0 : 63;                 // clamp: shuffle index always valid
        int i1 = (j1 < 63) ? j1 : 63;
        int s0 = __shfl(vidx, i0, 64);
        int s1 = __shfl(vidx, i1, 64);
        float g0 = (j0 < lim) ? 1.0f : 0.0f;
        float g1 = (j1 < lim) ? 1.0f : 0.0f;
        const uint4* r0 = (const uint4*)(xb + (size_t)s0 * IN_DIM + l8 * 16);
        const uint4* r1 = (const uint4*)(xb + (size_t)s1 * IN_DIM + l8 * 16);
        uint4 a0 = r0[0], a1 = r0[1];
        uint4 b0 = r1[0], b1 = r1[1];
        acc[0]  += g0 * bf_lo(a0.x); acc[1]  += g0 * bf_hi(a0.x);
        acc[2]  += g0 * bf_lo(a0.y); acc[3]  += g0 * bf_hi(a0.y);
        acc[4]  += g0 * bf_lo(a0.z); acc[5]  += g0 * bf_hi(a0.z);
        acc[6]  += g0 * bf_lo(a0.w); acc[7]  += g0 * bf_hi(a0.w);
        acc[8]  += g0 * bf_lo(a1.x); acc[9]  += g0 * bf_hi(a1.x);
        acc[10] += g0 * bf_lo(a1.y); acc[11] += g0 * bf_hi(a1.y);
        acc[12] += g0 * bf_lo(a1.z); acc[13] += g0 * bf_hi(a1.z);
        acc[14] += g0 * bf_lo(a1.w); acc[15] += g0 * bf_hi(a1.w);
        acc[0]  += g1 * bf_lo(b0.x); acc[1]  += g1 * bf_hi(b0.x);
        acc[2]  += g1 * bf_lo(b0.y); acc[3]  += g1 * bf_hi(b0.y);
        acc[4]  += g1 * bf_lo(b0.z); acc[5]  += g1 * bf_hi(b0.z);
        acc[6]  += g1 * bf_lo(b0.w); acc[7]  += g1 * bf_hi(b0.w);
        acc[8]  += g1 * bf_lo(b1.x); acc[9]  += g1 * bf_hi(b1.x);
        acc[10] += g1 * bf_lo(b1.y); acc[11] += g1 * bf_hi(b1.y);
        acc[12] += g1 * bf_lo(b1.z); acc[13] += g1 * bf_hi(b1.z);
        acc[14] += g1 * bf_lo(b1.w); acc[15] += g1 * bf_hi(b1.w);
    }
    // rare tail c > 64: per-lane global index loads, no shuffles
    for (int j = 64 + grp; j < c; j += 8) {
        int s0 = ssrc[start + j];
        const uint4* r0 = (const uint4*)(xb + (size_t)s0 * IN_DIM + l8 * 16);
        uint4 a0 = r0[0], a1 = r0[1];
        acc[0]  += bf_lo(a0.x); acc[1]  += bf_hi(a0.x); acc[2]  += bf_lo(a0.y); acc[3]  += bf_hi(a0.y);
        acc[4]  += bf_lo(a0.z); acc[5]  += bf_hi(a0.z); acc[6]  += bf_lo(a0.w); acc[7]  += bf_hi(a0.w);
        acc[8]  += bf_lo(a1.x); acc[9]  += bf_hi(a1.x); acc[10] += bf_lo(a1.y); acc[11] += bf_hi(a1.y);
        acc[12] += bf_lo(a1.z); acc[13] += bf_hi(a1.z); acc[14] += bf_lo(a1.w); acc[15] += bf_hi(a1.w);
    }
    #pragma unroll
    for (int k = 0; k < 16; k++) {
        acc[k] += __shfl_xor(acc[k], 8, 64);
        acc[k] += __shfl_xor(acc[k], 16, 64);
        acc[k] += __shfl_xor(acc[k], 32, 64);
    }
    if (grp == 0) {
        float dn = dis[node];
        const uint4* rs = (const uint4*)(xb + (size_t)node * IN_DIM + l8 * 16);
        uint4 a0 = rs[0], a1 = rs[1];
        acc[0]  += bf_lo(a0.x); acc[1]  += bf_hi(a0.x); acc[2]  += bf_lo(a0.y); acc[3]  += bf_hi(a0.y);
        acc[4]  += bf_lo(a0.z); acc[5]  += bf_hi(a0.z); acc[6]  += bf_lo(a0.w); acc[7]  += bf_hi(a0.w);
        acc[8]  += bf_lo(a1.x); acc[9]  += bf_hi(a1.x); acc[10] += bf_lo(a1.y); acc[11] += bf_hi(a1.y);
        acc[12] += bf_lo(a1.z); acc[13] += bf_hi(a1.z); acc[14] += bf_lo(a1.w); acc[15] += bf_hi(a1.w);
        bf16x8 o0, o1;
        #pragma unroll
        for (int k = 0; k < 8; k++) { o0[k] = f2bf(acc[k] * dn); o1[k] = f2bf(acc[k + 8] * dn); }
        short* dst0 = aggx + (size_t)node * IN_DIM + l8 * 16;
        *((bf16x8*)dst0) = o0;
        *((bf16x8*)(dst0 + 8)) = o1;
    }
}

// -------- fused MFMA GEMM: h2[r,:] = dis[r] * (relu(aggx[r,:]@W1 + b1) @ W2) ----------
#define H1_STRIDE 264
__global__ __launch_bounds__(256) void gemm_fused_kernel(const short* __restrict__ A,
                                                         const short* __restrict__ Bp1,
                                                         const short* __restrict__ Bp2,
                                                         const float* __restrict__ b1,
                                                         const float* __restrict__ dis,
                                                         short* __restrict__ h2, int M) {
    __shared__ short lds_h1[4][16][H1_STRIDE];
    int lane = threadIdx.x & 63;
    int w = threadIdx.x >> 6;
    int rowBase = blockIdx.x * 64 + w * 16;
    int arow = rowBase + (lane & 15);
    int kseg = lane >> 4;             // 0..3
    int col0 = lane & 15;

    // ---- phase A: h1 = relu(aggx @ W1 + b1), K=128, N=256 ----
    constexpr int NT1 = HID_DIM / 16;   // 16
    f32x4 acc1[NT1] = {};
    #pragma unroll
    for (int kt = 0; kt < IN_DIM / 32; kt++) {
        bf16x8 a = {};
        if (arow < M)
            a = *((const bf16x8*)(A + (size_t)arow * IN_DIM + kt * 32 + kseg * 8));
        #pragma unroll
        for (int nt = 0; nt < NT1; nt++) {
            bf16x8 b = *((const bf16x8*)(Bp1 + ((size_t)(kt * NT1 + nt) * 64 + lane) * 8));
            acc1[nt] = __builtin_amdgcn_mfma_f32_16x16x32_bf16(a, b, acc1[nt], 0, 0, 0);
        }
    }
    #pragma unroll
    for (int nt = 0; nt < NT1; nt++) {
        float bv = b1[nt * 16 + col0];
        #pragma unroll
        for (int i = 0; i < 4; i++) {
            float v = fmaxf(acc1[nt][i] + bv, 0.0f);
            lds_h1[w][kseg * 4 + i][nt * 16 + col0] = f2bf(v);
        }
    }
    // ---- phase B: h2 = (h1 @ W2) * dis, K=256, N=64; A-frags from own wave's LDS ----
    constexpr int NT2 = OUT_DIM / 16;   // 4
    f32x4 acc2[NT2] = {};
    #pragma unroll
    for (int kt = 0; kt < HID_DIM / 32; kt++) {
        bf16x8 a = *((const bf16x8*)&lds_h1[w][lane & 15][kt * 32 + kseg * 8]);
        #pragma unroll
        for (int nt = 0; nt < NT2; nt++) {
            bf16x8 b = *((const bf16x8*)(Bp2 + ((size_t)(kt * NT2 + nt) * 64 + lane) * 8));
            acc2[nt] = __builtin_amdgcn_mfma_f32_16x16x32_bf16(a, b, acc2[nt], 0, 0, 0);
        }
    }
    #pragma unroll
    for (int i = 0; i < 4; i++) {
        int r = rowBase + kseg * 4 + i;
        if (r >= M) continue;
        float sc = dis[r];
        #pragma unroll
        for (int nt = 0; nt < NT2; nt++)
            h2[(size_t)r * OUT_DIM + nt * 16 + col0] = f2bf(acc2[nt][i] * sc);
    }
}

// ------- layer-2 aggregate: wave per node, 8 groups x 8 lanes (16 B/lane/row),
// ------- wave-uniform shuffle rounds (gated FMA), + self-loop + bias + log_softmax ----
__global__ void agg2_kernel(const short* __restrict__ h2, const int* __restrict__ ssrc,
                            const int* __restrict__ offs, const int* __restrict__ cnt,
                            const float* __restrict__ dis, const float* __restrict__ b2,
                            float* __restrict__ out, int n) {
    int lane = threadIdx.x & 63;
    int node = blockIdx.x * 4 + (threadIdx.x >> 6);
    if (node >= n) return;
    int grp = lane >> 3, l8 = lane & 7;
    int start = offs[node], c = cnt[node];
    int vidx = (lane < c) ? ssrc[start + lane] : 0;
    float acc[8] = {};
    int lim = (c < 64) ? c : 64;
    int rounds = (lim + 15) >> 4;                     // wave-uniform
    for (int r = 0; r < rounds; r++) {
        int j0 = r * 16 + grp;
        int j1 = j0 + 8;
        int i0 = (j0 < 63) ? j0 : 63;
        int i1 = (j1 < 63) ? j1 : 63;
        int s0 = __shfl(vidx, i0, 64);
        int s1 = __shfl(vidx, i1, 64);
        float g0 = (j0 < lim) ? 1.0f : 0.0f;
        float g1 = (j1 < lim) ? 1.0f : 0.0f;
        uint4 p0 = *((const uint4*)(h2 + (size_t)s0 * OUT_DIM + l8 * 8));
        uint4 p1 = *((const uint4*)(h2 + (size_t)s1 * OUT_DIM + l8 * 8));
        acc[0] += g0 * bf_lo(p0.x); acc[1] += g0 * bf_hi(p0.x);
        acc[2] += g0 * bf_lo(p0.y); acc[3] += g0 * bf_hi(p0.y);
        acc[4] += g0 * bf_lo(p0.z); acc[5] += g0 * bf_hi(p0.z);
        acc[6] += g0 * bf_lo(p0.w); acc[7] += g0 * bf_hi(p0.w);
        acc[0] += g1 * bf_lo(p1.x); acc[1] += g1 * bf_hi(p1.x);
        acc[2] += g1 * bf_lo(p1.y); acc[3] += g1 * bf_hi(p1.y);
        acc[4] += g1 * bf_lo(p1.z); acc[5] += g1 * bf_hi(p1.z);
        acc[6] += g1 * bf_lo(p1.w); acc[7] += g1 * bf_hi(p1.w);
    }
    // rare tail c > 64
    for (int j = 64 + grp; j < c; j += 8) {
        int s0 = ssrc[start + j];
        uint4 p0 = *((const uint4*)(h2 + (size_t)s0 * OUT_DIM + l8 * 8));
        acc[0] += bf_lo(p0.x); acc[1] += bf_hi(p0.x); acc[2] += bf_lo(p0.y); acc[3] += bf_hi(p0.y);
        acc[4] += bf_lo(p0.z); acc[5] += bf_hi(p0.z); acc[6] += bf_lo(p0.w); acc[7] += bf_hi(p0.w);
    }
    #pragma unroll
    for (int k = 0; k < 8; k++) {
        acc[k] += __shfl_xor(acc[k], 8, 64);
        acc[k] += __shfl_xor(acc[k], 16, 64);
        acc[k] += __shfl_xor(acc[k], 32, 64);
    }
    // self-loop + dn scale + bias (cols l8*8 .. l8*8+7)
    float dn = dis[node];
    uint4 pv = *((const uint4*)(h2 + (size_t)node * OUT_DIM + l8 * 8));
    float4 bb0 = ((const float4*)b2)[l8 * 2];
    float4 bb1 = ((const float4*)b2)[l8 * 2 + 1];
    acc[0] = (acc[0] + bf_lo(pv.x)) * dn + bb0.x;
    acc[1] = (acc[1] + bf_hi(pv.x)) * dn + bb0.y;
    acc[2] = (acc[2] + bf_lo(pv.y)) * dn + bb0.z;
    acc[3] = (acc[3] + bf_hi(pv.y)) * dn + bb0.w;
    acc[4] = (acc[4] + bf_lo(pv.z)) * dn + bb1.x;
    acc[5] = (acc[5] + bf_hi(pv.z)) * dn + bb1.y;
    acc[6] = (acc[6] + bf_lo(pv.w)) * dn + bb1.z;
    acc[7] = (acc[7] + bf_hi(pv.w)) * dn + bb1.w;
    // log_softmax over 64 cols (8 l8-lanes x 8 regs)
    float m = acc[0];
    #pragma unroll
    for (int k = 1; k < 8; k++) m = fmaxf(m, acc[k]);
    #pragma unroll
    for (int off = 1; off < 8; off <<= 1) m = fmaxf(m, __shfl_xor(m, off, 64));
    float ex = 0.0f;
    #pragma unroll
    for (int k = 0; k < 8; k++) ex += expf(acc[k] - m);
    #pragma unroll
    for (int off = 1; off < 8; off <<= 1) ex += __shfl_xor(ex, off, 64);
    float ls = m + logf(ex);
    if (grp == 0) {
        float4 o0 = {acc[0] - ls, acc[1] - ls, acc[2] - ls, acc[3] - ls};
        float4 o1 = {acc[4] - ls, acc[5] - ls, acc[6] - ls, acc[7] - ls};
        ((float4*)(out + (size_t)node * OUT_DIM))[l8 * 2] = o0;
        ((float4*)(out + (size_t)node * OUT_DIM))[l8 * 2 + 1] = o1;
    }
}

extern "C" void kernel_launch(void* const* d_in, const int* in_sizes, int n_in,
                              void* d_out, int out_size, void* d_ws, size_t ws_size,
                              hipStream_t stream) {
    const float* x  = (const float*)d_in[0];
    const int*   ei = (const int*)d_in[1];
    const float* W1 = (const float*)d_in[2];
    const float* b1 = (const float*)d_in[3];
    const float* W2 = (const float*)d_in[4];
    const float* b2 = (const float*)d_in[5];
    float* out = (float*)d_out;
    char* ws = (char*)d_ws;

    const int* srcp = ei;
    const int* dstp = ei + N_EDGES;

    // workspace layout (256-aligned)
    int*   coarseCursor = (int*)(ws);              // 196 int (doubles as coarseCnt)
    int*   offs   = (int*)(ws + 4096);             // 50000 int
    int*   cntg   = (int*)(ws + 262144);           // 50000 int
    float* dis    = (float*)(ws + 524288);         // 50000 f32
    short* Bp1    = (short*)(ws + 786432);         // 64 KB
    short* Bp2    = (short*)(ws + 851968);         // 32 KB
    int*   ssrc   = (int*)(ws + 917504);           // 196*8192*4 = 6.4 MB
    uint2* sedge  = (uint2*)(ws + 7340032);        // 196*8192*8 = 12.8 MB (dead after part2)
    short* aggx   = (short*)(ws + 7340032);        // 12.8 MB, overlays sedge (live after part2)
    short* xb     = (short*)(ws + 20185088);       // 12.8 MB
    short* h2     = (short*)(ws + 32985088);       // 6.4 MB bf16

    hipMemsetAsync(coarseCursor, 0, NPART * 4, stream);

    part1_pack_kernel<<<NPB + 24, 256, 0, stream>>>(srcp, dstp, coarseCursor, sedge,
                                                    W1, W2, Bp1, Bp2, N_EDGES);
    part2_kernel<<<NPART, 256, 0, stream>>>(sedge, coarseCursor, offs, cntg, dis, ssrc,
                                            x, xb, N_NODES);
    agg1_kernel<<<(N_NODES + 3) / 4, 256, 0, stream>>>(xb, ssrc, offs, cntg, dis, aggx, N_NODES);
    gemm_fused_kernel<<<(N_NODES + 63) / 64, 256, 0, stream>>>(aggx, Bp1, Bp2, b1, dis,
                                                               h2, N_NODES);
    agg2_kernel<<<(N_NODES + 3) / 4, 256, 0, stream>>>(h2, ssrc, offs, cntg, dis, b2, out, N_NODES);
}